// Round 1
// baseline (339.646 us; speedup 1.0000x reference)
//
#include <hip/hip_runtime.h>

// GCNFirst: h[i,:] = (1/deg(i)) * sum over edges (i,p,j) of weights[p,j,:]
// weights: (r=16, n=100000, e=16) f32; edges: E=3.2M (src, rel, dst) i32.

static constexpr int EDIM = 16;
static constexpr int NREL = 16;

// Pass 1: out-degree histogram (fp32 so pass 2 can divide directly).
__global__ void deg_kernel(const int* __restrict__ src, float* __restrict__ deg, int E) {
    int k = blockIdx.x * blockDim.x + threadIdx.x;
    if (k < E) {
        atomicAdd(&deg[src[k]], 1.0f);
    }
}

// Pass 2: 16 lanes per edge. lane l handles feature element l.
// Weight read: 64B contiguous per edge (coalesced within the 16-lane group).
// Output: 16 atomicAdds into 64 contiguous bytes of h[src].
__global__ void scatter_kernel(const float* __restrict__ w,
                               const int* __restrict__ src,
                               const int* __restrict__ rel,
                               const int* __restrict__ dst,
                               const float* __restrict__ deg,
                               float* __restrict__ out,
                               int E, int n) {
    long long tid = (long long)blockIdx.x * blockDim.x + threadIdx.x;
    int lane = (int)(tid & (EDIM - 1));
    int k = (int)(tid >> 4);
    if (k >= E) return;

    int s = src[k];
    int p = rel[k];
    int j = dst[k];
    float v = 1.0f / deg[s];  // deg[s] >= 1 whenever edge (s,...) exists
    float wv = w[((size_t)p * n + j) * EDIM + lane];
    atomicAdd(&out[(size_t)s * EDIM + lane], wv * v);
}

extern "C" void kernel_launch(void* const* d_in, const int* in_sizes, int n_in,
                              void* d_out, int out_size, void* d_ws, size_t ws_size,
                              hipStream_t stream) {
    const float* w   = (const float*)d_in[0];
    const int*   src = (const int*)d_in[1];
    const int*   rel = (const int*)d_in[2];
    const int*   dst = (const int*)d_in[3];
    float* out = (float*)d_out;
    float* deg = (float*)d_ws;

    int E = in_sizes[1];
    int n = in_sizes[0] / (NREL * EDIM);  // weights flat = r*n*e

    // Harness poisons d_out/d_ws to 0xAA and does not re-poison between
    // replays — we must zero both every call.
    hipMemsetAsync(deg, 0, (size_t)n * sizeof(float), stream);
    hipMemsetAsync(out, 0, (size_t)out_size * sizeof(float), stream);

    int dblocks = (E + 255) / 256;
    deg_kernel<<<dblocks, 256, 0, stream>>>(src, deg, E);

    long long total = (long long)E * EDIM;
    int sblocks = (int)((total + 255) / 256);
    scatter_kernel<<<sblocks, 256, 0, stream>>>(w, src, rel, dst, deg, out, E, n);
}